// Round 4
// baseline (88.401 us; speedup 1.0000x reference)
//
#include <hip/hip_runtime.h>

#define D 128
#define NS 16
#define BATCH 16384
#define TILE 32
#define CHUNK 512              // sidx indices scanned per consumer block
#define NCH (BATCH / CHUNK)    // 32 chunks -> grid (32,16) = 512 blocks

typedef __attribute__((ext_vector_type(8))) short short8;
typedef __attribute__((ext_vector_type(4))) float f32x4;

__device__ __forceinline__ unsigned short f2bf(float f) {
  unsigned u = __builtin_bit_cast(unsigned, f);
  u += 0x7FFFu + ((u >> 16) & 1u);   // round-to-nearest-even
  return (unsigned short)(u >> 16);
}

// ---------------------------------------------------------------------------
// prep: transpose+convert A/C -> bf16 At[e][d], Ct[e][d] (proven R2/R3 path,
// zero LDS bank conflicts measured). List-building is GONE (R4): consumers
// scan sidx themselves, killing memset node + atomics + cross-XCD hand-off.
// ---------------------------------------------------------------------------
__global__ __launch_bounds__(256) void prep_kernel(
    const float* __restrict__ A_all, const float* __restrict__ C_all,
    unsigned short* __restrict__ At, unsigned short* __restrict__ Ct) {
  const int b = blockIdx.x, tid = threadIdx.x;
  __shared__ float T[32][129];
  const int mat = b >> 6, r = b & 63, s = r >> 2, slab = r & 3;
  const float* in = (mat ? C_all : A_all) + (size_t)s * D * D;
  unsigned short* outp = (mat ? Ct : At) + (size_t)s * D * D;
  const int e0 = slab * 32;
  const int ecol = (tid & 7) * 4;
  const int drow = tid >> 3;
#pragma unroll
  for (int i = 0; i < 4; i++) {
    const int d = drow + 32 * i;
    const float4 v = *(const float4*)(in + (size_t)d * D + e0 + ecol);
    T[ecol + 0][d] = v.x;
    T[ecol + 1][d] = v.y;
    T[ecol + 2][d] = v.z;
    T[ecol + 3][d] = v.w;
  }
  __syncthreads();
  const int e = tid >> 3;
  const int d0 = (tid & 7) * 16;
  unsigned short p[16];
#pragma unroll
  for (int k = 0; k < 16; k++) p[k] = f2bf(T[e][d0 + k]);
  unsigned short* dst = outp + (size_t)(e0 + e) * D + d0;
  *(uint4*)(dst) = *(const uint4*)(p);
  *(uint4*)(dst + 8) = *(const uint4*)(p + 8);
}

// ---------------------------------------------------------------------------
// ssm: block (chunk j, state s) scans sidx[j*512..+512), compacts matching
// rows via ballot (order irrelevant), then 32-row MFMA tiles.
//  At+Ct live in 64 VGPRs from t=0; LDS Ws re-staged from regs per phase.
//  MFMA 16x16x32 bf16 layouts (HW-verified):
//    A: A[m=lane&15][k=(lane>>4)*8+j]   B: B[k=(lane>>4)*8+j][n=lane&15]
//    C/D: col=lane&15, row=(lane>>4)*4+reg
//  LDS = 34.8(Ws) + 8.7(Xs) + 8.7(Hs) + 2(rowlist) ~= 54.3 KB -> 2 blocks/CU
// ---------------------------------------------------------------------------
__global__ __launch_bounds__(256, 2) void ssm_kernel(
    const float* __restrict__ x,
    const int* __restrict__ sidx,
    const unsigned short* __restrict__ At,
    const unsigned short* __restrict__ Ct,
    float* __restrict__ out) {
  __shared__ unsigned short Xs[TILE][136];  // X tile (bf16)
  __shared__ unsigned short Hs[TILE][136];  // relu(X@A) tile (bf16)
  __shared__ unsigned short Ws[D][136];     // At, then Ct (per phase, from regs)
  __shared__ int rowlist[CHUNK];
  __shared__ int wcnt[8];

  const int s = blockIdx.y;
  const int c0 = blockIdx.x * CHUNK;
  const int tid = threadIdx.x;
  const int lane = tid & 63, w = tid >> 6;
  const int l15 = lane & 15, quad = lane >> 4;
  const int wr = w & 1, wc = w >> 1;

  // ---- issue ALL expert-matrix loads at t=0 (64 VGPRs) ----
  uint4 atr[8], ctr[8];
  {
    const uint4* gA = (const uint4*)(At + (size_t)s * D * D);
    const uint4* gC = (const uint4*)(Ct + (size_t)s * D * D);
#pragma unroll
    for (int i = 0; i < 8; i++) { atr[i] = gA[i * 256 + tid]; ctr[i] = gC[i * 256 + tid]; }
  }

  // ---- scan + ballot compaction (2 rounds of 256) ----
  const int v0 = sidx[c0 + tid];
  const int v1 = sidx[c0 + 256 + tid];
  const unsigned long long lanelt = (1ull << lane) - 1ull;
  const unsigned long long m0 = __ballot(v0 == s);
  const unsigned long long m1 = __ballot(v1 == s);
  if (lane == 0) { wcnt[w] = (int)__popcll(m0); wcnt[4 + w] = (int)__popcll(m1); }
  __syncthreads();
  int pre0 = 0, pre1 = 0, tot0 = 0, cnt = 0;
#pragma unroll
  for (int ww = 0; ww < 4; ww++) {
    if (ww < w) { pre0 += wcnt[ww]; pre1 += wcnt[4 + ww]; }
    tot0 += wcnt[ww];
    cnt += wcnt[ww] + wcnt[4 + ww];
  }
  if (v0 == s) rowlist[pre0 + (int)__popcll(m0 & lanelt)] = c0 + tid;
  if (v1 == s) rowlist[tot0 + pre1 + (int)__popcll(m1 & lanelt)] = c0 + 256 + tid;
  __syncthreads();

  // ---- MFMA tiles over collected rows ----
  for (int i0 = 0; i0 < cnt; i0 += TILE) {          // cnt is block-uniform
    if (i0) __syncthreads();                        // prior phase-2 Ws reads done

    // Ws <- At (from regs)
#pragma unroll
    for (int i = 0; i < 8; i++) {
      const int c = i * 256 + tid;
      *(uint4*)&Ws[c >> 4][(c & 15) * 8] = atr[i];
    }
    // gather X rows (8 threads/row, fp32 -> bf16)
    {
      const int r = tid >> 3, q = tid & 7;
      const int rl = i0 + r;
      const int rid = (rl < cnt) ? rowlist[rl] : -1;
      unsigned short* xr = &Xs[r][q * 16];
      if (rid >= 0) {
        const float4* src = (const float4*)(x + (size_t)rid * D + q * 16);
#pragma unroll
        for (int i = 0; i < 4; i++) {
          float4 v = src[i];
          ushort4 p;
          p.x = f2bf(v.x); p.y = f2bf(v.y); p.z = f2bf(v.z); p.w = f2bf(v.w);
          *(ushort4*)(xr + i * 4) = p;
        }
      } else {
        ushort4 z; z.x = z.y = z.z = z.w = 0;
#pragma unroll
        for (int i = 0; i < 4; i++) *(ushort4*)(xr + i * 4) = z;
      }
    }
    __syncthreads();

    // phase 1: H = relu(X @ A); wave = (rows 16*wr.., cols 64*wc..)
    f32x4 acc[4];
#pragma unroll
    for (int nb = 0; nb < 4; nb++) acc[nb] = (f32x4){0.f, 0.f, 0.f, 0.f};
#pragma unroll
    for (int kb = 0; kb < 4; kb++) {
      short8 aF = *(const short8*)&Xs[wr * 16 + l15][kb * 32 + quad * 8];
#pragma unroll
      for (int nb = 0; nb < 4; nb++) {
        short8 bF = *(const short8*)&Ws[wc * 64 + nb * 16 + l15][kb * 32 + quad * 8];
        acc[nb] = __builtin_amdgcn_mfma_f32_16x16x32_bf16(aF, bF, acc[nb], 0, 0, 0);
      }
    }
#pragma unroll
    for (int nb = 0; nb < 4; nb++)
#pragma unroll
      for (int rr = 0; rr < 4; rr++) {
        float v = acc[nb][rr];
        Hs[wr * 16 + quad * 4 + rr][wc * 64 + nb * 16 + l15] = f2bf(v > 0.f ? v : 0.f);
      }
    __syncthreads();   // phase-1 Ws/Xs reads done

    // Ws <- Ct (from regs)
#pragma unroll
    for (int i = 0; i < 8; i++) {
      const int c = i * 256 + tid;
      *(uint4*)&Ws[c >> 4][(c & 15) * 8] = ctr[i];
    }
    __syncthreads();

    // phase 2: out = H @ C
#pragma unroll
    for (int nb = 0; nb < 4; nb++) acc[nb] = (f32x4){0.f, 0.f, 0.f, 0.f};
#pragma unroll
    for (int kb = 0; kb < 4; kb++) {
      short8 aF = *(const short8*)&Hs[wr * 16 + l15][kb * 32 + quad * 8];
#pragma unroll
      for (int nb = 0; nb < 4; nb++) {
        short8 bF = *(const short8*)&Ws[wc * 64 + nb * 16 + l15][kb * 32 + quad * 8];
        acc[nb] = __builtin_amdgcn_mfma_f32_16x16x32_bf16(aF, bF, acc[nb], 0, 0, 0);
      }
    }

    // scatter stores
#pragma unroll
    for (int rr = 0; rr < 4; rr++) {
      const int rl = wr * 16 + quad * 4 + rr;
      if (i0 + rl < cnt) {
        float* orow = out + (size_t)rowlist[i0 + rl] * D + wc * 64 + l15;
#pragma unroll
        for (int nb = 0; nb < 4; nb++) orow[nb * 16] = acc[nb][rr];
      }
    }
  }
}

extern "C" void kernel_launch(void* const* d_in, const int* in_sizes, int n_in,
                              void* d_out, int out_size, void* d_ws, size_t ws_size,
                              hipStream_t stream) {
  const float* x = (const float*)d_in[0];
  const int* sidx = (const int*)d_in[1];
  const float* A_all = (const float*)d_in[2];
  const float* C_all = (const float*)d_in[3];
  float* out = (float*)d_out;

  // ws: At(512KB bf16) | Ct(512KB bf16)
  unsigned short* At = (unsigned short*)d_ws;
  unsigned short* Ct = At + NS * D * D;

  prep_kernel<<<128, 256, 0, stream>>>(A_all, C_all, At, Ct);
  ssm_kernel<<<dim3(NCH, NS), 256, 0, stream>>>(x, sidx, At, Ct, out);
}

// Round 5
// 79.156 us; speedup vs baseline: 1.1168x; 1.1168x over previous
//
#include <hip/hip_runtime.h>

#define D 128
#define NS 16
#define BATCH 16384
#define TILE 64
#define CHUNK 512
#define NCH (BATCH / CHUNK)   // 32 chunks -> grid (32,16) = 512 blocks

typedef __attribute__((ext_vector_type(8))) short short8;
typedef __attribute__((ext_vector_type(4))) float f32x4;

__device__ __forceinline__ unsigned short f2bf(float f) {
  unsigned u = __builtin_bit_cast(unsigned, f);
  u += 0x7FFFu + ((u >> 16) & 1u);   // round-to-nearest-even
  return (unsigned short)(u >> 16);
}

// ---------------------------------------------------------------------------
// Single fused kernel (R5): block (chunk j, state s)
//   1. scan sidx[j*512..+512), ballot-compact matching rows (R4 path)
//   2. transpose+convert A[s], C[s] fp32 -> bf16 into 64 VGPRs, via a
//      32x129 fp32 LDS staging buffer ALIASED onto the Ws region
//   3. 64-row MFMA tiles: H = relu(X@A); out = H@C
// No workspace, no prep kernel, no memset: graph = 1 node.
//  MFMA 16x16x32 bf16 layouts (HW-verified):
//    A: A[m=lane&15][k=(lane>>4)*8+j]   B: B[k=(lane>>4)*8+j][n=lane&15]
//    C/D: col=lane&15, row=(lane>>4)*4+reg
//  LDS: Ws 34.8K (T 16.5K aliased) + Xs 17.4K + Hs 17.4K + rowlist 2K = 70K
//       -> 2 blocks/CU; stride 136 proven conflict-free (R2-R4: conflicts=0)
// ---------------------------------------------------------------------------
__global__ __launch_bounds__(256, 2) void ssm_fused(
    const float* __restrict__ x,
    const int* __restrict__ sidx,
    const float* __restrict__ A_all,
    const float* __restrict__ C_all,
    float* __restrict__ out) {
  __shared__ __align__(16) char smemW[D * 136 * 2];  // Ws | aliased T
  unsigned short (*Ws)[136] = (unsigned short (*)[136])smemW;
  float (*T)[129] = (float (*)[129])smemW;           // 32x129 fp32 = 16.5 KB
  __shared__ unsigned short Xs[TILE][136];
  __shared__ unsigned short Hs[TILE][136];
  __shared__ int rowlist[CHUNK];
  __shared__ int wcnt[8];

  const int s = blockIdx.y;
  const int c0 = blockIdx.x * CHUNK;
  const int tid = threadIdx.x;
  const int lane = tid & 63, w = tid >> 6;
  const int l15 = lane & 15, quad = lane >> 4;
  const int wr = w & 1, wc = w >> 1;

  // ---- 1. scan + ballot compaction (2 rounds of 256) ----
  const int v0 = sidx[c0 + tid];
  const int v1 = sidx[c0 + 256 + tid];
  const unsigned long long lanelt = (1ull << lane) - 1ull;
  const unsigned long long m0 = __ballot(v0 == s);
  const unsigned long long m1 = __ballot(v1 == s);
  if (lane == 0) { wcnt[w] = (int)__popcll(m0); wcnt[4 + w] = (int)__popcll(m1); }
  __syncthreads();
  int pre0 = 0, pre1 = 0, tot0 = 0, cnt = 0;
#pragma unroll
  for (int ww = 0; ww < 4; ww++) {
    if (ww < w) { pre0 += wcnt[ww]; pre1 += wcnt[4 + ww]; }
    tot0 += wcnt[ww];
    cnt += wcnt[ww] + wcnt[4 + ww];
  }
  if (v0 == s) rowlist[pre0 + (int)__popcll(m0 & lanelt)] = c0 + tid;
  if (v1 == s) rowlist[tot0 + pre1 + (int)__popcll(m1 & lanelt)] = c0 + 256 + tid;
  if (cnt == 0) return;  // cnt is block-uniform: whole block exits together

  // ---- 2. per-block transpose+convert A[s], C[s] -> atr/ctr VGPRs ----
  uint4 atr[8], ctr[8];
  {
    const float* __restrict__ srcA = A_all + (size_t)s * D * D;
    const float* __restrict__ srcC = C_all + (size_t)s * D * D;
    const int ecol = (tid & 7) * 4;
    const int drow = tid >> 3;
#pragma unroll
    for (int mat = 0; mat < 2; mat++) {
      const float* __restrict__ src = mat ? srcC : srcA;
#pragma unroll
      for (int sl = 0; sl < 4; sl++) {
        const int e0 = sl * 32;
        __syncthreads();  // T free (rowlist done / prior slab consumed)
#pragma unroll
        for (int i = 0; i < 4; i++) {
          const int d = drow + 32 * i;
          const float4 v = *(const float4*)(src + (size_t)d * D + e0 + ecol);
          T[ecol + 0][d] = v.x;
          T[ecol + 1][d] = v.y;
          T[ecol + 2][d] = v.z;
          T[ecol + 3][d] = v.w;
        }
        __syncthreads();
#pragma unroll
        for (int ii = 0; ii < 2; ii++) {
          const int c = (2 * sl + ii) * 256 + tid;
          const int e = (c >> 4) - e0;      // in [0,32)
          const int d0 = (c & 15) * 8;
          unsigned short p[8];
#pragma unroll
          for (int k = 0; k < 8; k++) p[k] = f2bf(T[e][d0 + k]);
          if (mat) ctr[2 * sl + ii] = *(const uint4*)p;
          else     atr[2 * sl + ii] = *(const uint4*)p;
        }
      }
    }
    __syncthreads();  // last T reads done before Ws (aliased) is written
  }

  // ---- 3. MFMA tiles over collected rows (cnt ~ 32: one pass typical) ----
#pragma unroll 1
  for (int i0 = 0; i0 < cnt; i0 += TILE) {
    if (i0) __syncthreads();  // prior phase-2 Ws reads done

    // Ws <- At (from regs)
#pragma unroll
    for (int i = 0; i < 8; i++) {
      const int c = i * 256 + tid;
      *(uint4*)&Ws[c >> 4][(c & 15) * 8] = atr[i];
    }
    // gather 64 X rows (4 threads/row, fp32 -> bf16)
    {
      const int r = tid >> 2, q = tid & 3;
      const int rid = (i0 + r < cnt) ? rowlist[i0 + r] : -1;
      unsigned short* xr = &Xs[r][q * 32];
      if (rid >= 0) {
        const float4* src = (const float4*)(x + (size_t)rid * D + q * 32);
#pragma unroll
        for (int i = 0; i < 8; i++) {
          float4 v = src[i];
          ushort4 p;
          p.x = f2bf(v.x); p.y = f2bf(v.y); p.z = f2bf(v.z); p.w = f2bf(v.w);
          *(ushort4*)(xr + i * 4) = p;
        }
      } else {
        ushort4 z; z.x = z.y = z.z = z.w = 0;
#pragma unroll
        for (int i = 0; i < 8; i++) *(ushort4*)(xr + i * 4) = z;
      }
    }
    __syncthreads();

    // phase 1: H = relu(X @ A); wave (wr,wc): rows 32*wr..+32, cols 64*wc..+64
    f32x4 acc[2][4];
#pragma unroll
    for (int ti = 0; ti < 2; ti++)
#pragma unroll
      for (int nb = 0; nb < 4; nb++) acc[ti][nb] = (f32x4){0.f, 0.f, 0.f, 0.f};
#pragma unroll
    for (int kb = 0; kb < 4; kb++) {
      short8 aF0 = *(const short8*)&Xs[(wr * 2 + 0) * 16 + l15][kb * 32 + quad * 8];
      short8 aF1 = *(const short8*)&Xs[(wr * 2 + 1) * 16 + l15][kb * 32 + quad * 8];
#pragma unroll
      for (int nb = 0; nb < 4; nb++) {
        short8 bF = *(const short8*)&Ws[wc * 64 + nb * 16 + l15][kb * 32 + quad * 8];
        acc[0][nb] = __builtin_amdgcn_mfma_f32_16x16x32_bf16(aF0, bF, acc[0][nb], 0, 0, 0);
        acc[1][nb] = __builtin_amdgcn_mfma_f32_16x16x32_bf16(aF1, bF, acc[1][nb], 0, 0, 0);
      }
    }
#pragma unroll
    for (int ti = 0; ti < 2; ti++)
#pragma unroll
      for (int nb = 0; nb < 4; nb++)
#pragma unroll
        for (int rr = 0; rr < 4; rr++) {
          float v = acc[ti][nb][rr];
          Hs[(wr * 2 + ti) * 16 + quad * 4 + rr][wc * 64 + nb * 16 + l15] =
              f2bf(v > 0.f ? v : 0.f);
        }
    __syncthreads();  // phase-1 Ws/Xs reads done

    // Ws <- Ct (from regs)
#pragma unroll
    for (int i = 0; i < 8; i++) {
      const int c = i * 256 + tid;
      *(uint4*)&Ws[c >> 4][(c & 15) * 8] = ctr[i];
    }
    __syncthreads();

    // phase 2: out = H @ C
#pragma unroll
    for (int ti = 0; ti < 2; ti++)
#pragma unroll
      for (int nb = 0; nb < 4; nb++) acc[ti][nb] = (f32x4){0.f, 0.f, 0.f, 0.f};
#pragma unroll
    for (int kb = 0; kb < 4; kb++) {
      short8 aF0 = *(const short8*)&Hs[(wr * 2 + 0) * 16 + l15][kb * 32 + quad * 8];
      short8 aF1 = *(const short8*)&Hs[(wr * 2 + 1) * 16 + l15][kb * 32 + quad * 8];
#pragma unroll
      for (int nb = 0; nb < 4; nb++) {
        short8 bF = *(const short8*)&Ws[wc * 64 + nb * 16 + l15][kb * 32 + quad * 8];
        acc[0][nb] = __builtin_amdgcn_mfma_f32_16x16x32_bf16(aF0, bF, acc[0][nb], 0, 0, 0);
        acc[1][nb] = __builtin_amdgcn_mfma_f32_16x16x32_bf16(aF1, bF, acc[1][nb], 0, 0, 0);
      }
    }

    // scatter stores (fp32)
#pragma unroll
    for (int ti = 0; ti < 2; ti++)
#pragma unroll
      for (int rr = 0; rr < 4; rr++) {
        const int rl = (wr * 2 + ti) * 16 + quad * 4 + rr;
        if (i0 + rl < cnt) {
          float* orow = out + (size_t)rowlist[i0 + rl] * D + wc * 64 + l15;
#pragma unroll
          for (int nb = 0; nb < 4; nb++) orow[nb * 16] = acc[ti][nb][rr];
        }
      }
  }
}

extern "C" void kernel_launch(void* const* d_in, const int* in_sizes, int n_in,
                              void* d_out, int out_size, void* d_ws, size_t ws_size,
                              hipStream_t stream) {
  const float* x = (const float*)d_in[0];
  const int* sidx = (const int*)d_in[1];
  const float* A_all = (const float*)d_in[2];
  const float* C_all = (const float*)d_in[3];
  float* out = (float*)d_out;

  ssm_fused<<<dim3(NCH, NS), 256, 0, stream>>>(x, sidx, A_all, C_all, out);
}

// Round 6
// 73.958 us; speedup vs baseline: 1.1953x; 1.0703x over previous
//
#include <hip/hip_runtime.h>

#define D 128
#define NS 16
#define BATCH 16384
#define TILE 64
#define CHUNK 512
#define WP 130   // Ws row stride (bf16 elems): (row + l15/2)%32 banks -> 2-way only

typedef __attribute__((ext_vector_type(8))) short short8;
typedef __attribute__((ext_vector_type(4))) float f32x4;

__device__ __forceinline__ unsigned short f2bf(float f) {
  unsigned u = __builtin_bit_cast(unsigned, f);
  u += 0x7FFFu + ((u >> 16) & 1u);   // round-to-nearest-even
  return (unsigned short)(u >> 16);
}

__device__ __forceinline__ uint4 pack8(float4 a, float4 b) {
  unsigned short p[8];
  p[0] = f2bf(a.x); p[1] = f2bf(a.y); p[2] = f2bf(a.z); p[3] = f2bf(a.w);
  p[4] = f2bf(b.x); p[5] = f2bf(b.y); p[6] = f2bf(b.z); p[7] = f2bf(b.w);
  return *(const uint4*)p;
}

// ---------------------------------------------------------------------------
// R6 single kernel. Insight: for BOTH matmuls (x@A and H@C) the expert matrix
// is the MFMA B-operand with k = row index, so its NATIVE row-major layout IS
// B[k][n] — no transpose needed anywhere. B-frag = 8x ds_read_u16 column
// stripe; with stride WP=130 the stripe is bank-conflict-free (2-way only).
//   block b: s = (b&7)|((b>>3&1)<<3), chunk = b>>4  -> same-state blocks
//   cluster on one XCD (b%8) for A[s]/C[s] L2 locality.
//   1. scan sidx chunk, ballot-compact rows
//   2. A[s],C[s] fp32 -> bf16 into 64 VGPRs (coalesced, native layout)
//   3. per 64-row tile: stage Ws<-atr, gather X; MFMA; H over Xs (aliased,
//      written after barrier); stage Ws<-ctr; MFMA; scatter stores.
//  MFMA 16x16x32 bf16 layouts (HW-verified):
//    A: A[m=lane&15][k=(lane>>4)*8+j]   B: B[k=(lane>>4)*8+j][n=lane&15]
//    C/D: col=lane&15, row=(lane>>4)*4+reg
//  LDS: Ws 33.3K + XH 17.4K + rowlist 2K = 52.8K -> not the occupancy limiter
// ---------------------------------------------------------------------------
__global__ __launch_bounds__(256, 2) void ssm_fused(
    const float* __restrict__ x,
    const int* __restrict__ sidx,
    const float* __restrict__ A_all,
    const float* __restrict__ C_all,
    float* __restrict__ out) {
  __shared__ unsigned short Ws[D * WP];     // A then C, native [row][col]
  __shared__ unsigned short XH[TILE][136];  // X tile, then H tile (aliased)
  __shared__ int rowlist[CHUNK];
  __shared__ int wcnt[8];

  const int b = blockIdx.x;
  const int s = (b & 7) | (((b >> 3) & 1) << 3);
  const int c0 = (b >> 4) * CHUNK;
  const int tid = threadIdx.x;
  const int lane = tid & 63, w = tid >> 6;
  const int l15 = lane & 15, quad = lane >> 4;
  const int wr = w & 1, wc = w >> 1;

  // ---- 1. scan chunk (loads first; ballots overlap the A/C loads below) --
  const int v0 = sidx[c0 + tid];
  const int v1 = sidx[c0 + 256 + tid];

  // ---- 2. A[s], C[s] -> bf16 regs, NATIVE layout (no transpose) ----
  uint4 atr[8], ctr[8];
  {
    const float* __restrict__ gA = A_all + (size_t)s * D * D;
    const float* __restrict__ gC = C_all + (size_t)s * D * D;
#pragma unroll
    for (int i = 0; i < 8; i++) {
      const int c = i * 256 + tid;             // 8 consecutive elems each
      float4 a0 = *(const float4*)(gA + (size_t)c * 8);
      float4 a1 = *(const float4*)(gA + (size_t)c * 8 + 4);
      float4 e0 = *(const float4*)(gC + (size_t)c * 8);
      float4 e1 = *(const float4*)(gC + (size_t)c * 8 + 4);
      atr[i] = pack8(a0, a1);
      ctr[i] = pack8(e0, e1);
    }
  }

  // ---- ballot compaction ----
  const unsigned long long lanelt = (1ull << lane) - 1ull;
  const unsigned long long m0 = __ballot(v0 == s);
  const unsigned long long m1 = __ballot(v1 == s);
  if (lane == 0) { wcnt[w] = (int)__popcll(m0); wcnt[4 + w] = (int)__popcll(m1); }
  __syncthreads();
  int pre0 = 0, pre1 = 0, tot0 = 0, cnt = 0;
#pragma unroll
  for (int ww = 0; ww < 4; ww++) {
    if (ww < w) { pre0 += wcnt[ww]; pre1 += wcnt[4 + ww]; }
    tot0 += wcnt[ww];
    cnt += wcnt[ww] + wcnt[4 + ww];
  }
  if (v0 == s) rowlist[pre0 + (int)__popcll(m0 & lanelt)] = c0 + tid;
  if (v1 == s) rowlist[tot0 + pre1 + (int)__popcll(m1 & lanelt)] = c0 + 256 + tid;
  if (cnt == 0) return;  // block-uniform

  // ---- 3. MFMA tiles ----
#pragma unroll 1
  for (int i0 = 0; i0 < cnt; i0 += TILE) {
    __syncthreads();  // rowlist ready (pass 0) / prior pass LDS reads done

    // Ws <- A (native, from regs); 4B-aligned dword writes, 2-way banks
#pragma unroll
    for (int i = 0; i < 8; i++) {
      const int c = i * 256 + tid;
      const int base = (c >> 4) * WP + (c & 15) * 8;
      const unsigned* pw = (const unsigned*)&atr[i];
#pragma unroll
      for (int k = 0; k < 4; k++) *(unsigned*)&Ws[base + k * 2] = pw[k];
    }
    // gather 64 X rows (4 threads/row, fp32 -> bf16)
    {
      const int r = tid >> 2, q = tid & 3;
      const int rid = (i0 + r < cnt) ? rowlist[i0 + r] : -1;
      unsigned short* xr = &XH[r][q * 32];
      if (rid >= 0) {
        const float4* src = (const float4*)(x + (size_t)rid * D + q * 32);
#pragma unroll
        for (int i = 0; i < 4; i++) {
          float4 va = src[2 * i];
          float4 vb = src[2 * i + 1];
          *(uint4*)(xr + i * 8) = pack8(va, vb);
        }
      } else {
        uint4 z = {0, 0, 0, 0};
#pragma unroll
        for (int i = 0; i < 4; i++) *(uint4*)(xr + i * 8) = z;
      }
    }
    __syncthreads();

    // phase 1: acc = X @ A ; wave (wr,wc): rows 32*wr..+32, cols 64*wc..+64
    f32x4 acc[2][4];
#pragma unroll
    for (int ti = 0; ti < 2; ti++)
#pragma unroll
      for (int nb = 0; nb < 4; nb++) acc[ti][nb] = (f32x4){0.f, 0.f, 0.f, 0.f};
#pragma unroll
    for (int kb = 0; kb < 4; kb++) {
      short8 aF0 = *(const short8*)&XH[(wr * 2 + 0) * 16 + l15][kb * 32 + quad * 8];
      short8 aF1 = *(const short8*)&XH[(wr * 2 + 1) * 16 + l15][kb * 32 + quad * 8];
      const int rbase = (kb * 32 + quad * 8) * WP;
#pragma unroll
      for (int nb = 0; nb < 4; nb++) {
        const int col = wc * 64 + nb * 16 + l15;
        short8 bF;
#pragma unroll
        for (int j = 0; j < 8; j++) bF[j] = (short)Ws[rbase + j * WP + col];
        acc[0][nb] = __builtin_amdgcn_mfma_f32_16x16x32_bf16(aF0, bF, acc[0][nb], 0, 0, 0);
        acc[1][nb] = __builtin_amdgcn_mfma_f32_16x16x32_bf16(aF1, bF, acc[1][nb], 0, 0, 0);
      }
    }
    __syncthreads();  // all phase-1 reads of XH(x) and Ws(A) done

    // H = relu(acc) -> XH (aliased over X: safe, we're past the barrier)
#pragma unroll
    for (int ti = 0; ti < 2; ti++)
#pragma unroll
      for (int nb = 0; nb < 4; nb++)
#pragma unroll
        for (int rr = 0; rr < 4; rr++) {
          float v = acc[ti][nb][rr];
          XH[(wr * 2 + ti) * 16 + quad * 4 + rr][wc * 64 + nb * 16 + l15] =
              f2bf(v > 0.f ? v : 0.f);
        }
    // Ws <- C (native, from regs)
#pragma unroll
    for (int i = 0; i < 8; i++) {
      const int c = i * 256 + tid;
      const int base = (c >> 4) * WP + (c & 15) * 8;
      const unsigned* pw = (const unsigned*)&ctr[i];
#pragma unroll
      for (int k = 0; k < 4; k++) *(unsigned*)&Ws[base + k * 2] = pw[k];
    }
    __syncthreads();

    // phase 2: out = H @ C
#pragma unroll
    for (int ti = 0; ti < 2; ti++)
#pragma unroll
      for (int nb = 0; nb < 4; nb++) acc[ti][nb] = (f32x4){0.f, 0.f, 0.f, 0.f};
#pragma unroll
    for (int kb = 0; kb < 4; kb++) {
      short8 aF0 = *(const short8*)&XH[(wr * 2 + 0) * 16 + l15][kb * 32 + quad * 8];
      short8 aF1 = *(const short8*)&XH[(wr * 2 + 1) * 16 + l15][kb * 32 + quad * 8];
      const int rbase = (kb * 32 + quad * 8) * WP;
#pragma unroll
      for (int nb = 0; nb < 4; nb++) {
        const int col = wc * 64 + nb * 16 + l15;
        short8 bF;
#pragma unroll
        for (int j = 0; j < 8; j++) bF[j] = (short)Ws[rbase + j * WP + col];
        acc[0][nb] = __builtin_amdgcn_mfma_f32_16x16x32_bf16(aF0, bF, acc[0][nb], 0, 0, 0);
        acc[1][nb] = __builtin_amdgcn_mfma_f32_16x16x32_bf16(aF1, bF, acc[1][nb], 0, 0, 0);
      }
    }

    // scatter stores (fp32, 64B segments)
#pragma unroll
    for (int ti = 0; ti < 2; ti++)
#pragma unroll
      for (int rr = 0; rr < 4; rr++) {
        const int rl = (wr * 2 + ti) * 16 + quad * 4 + rr;
        if (i0 + rl < cnt) {
          float* orow = out + (size_t)rowlist[i0 + rl] * D + wc * 64 + l15;
#pragma unroll
          for (int nb = 0; nb < 4; nb++) orow[nb * 16] = acc[ti][nb][rr];
        }
      }
  }
}

extern "C" void kernel_launch(void* const* d_in, const int* in_sizes, int n_in,
                              void* d_out, int out_size, void* d_ws, size_t ws_size,
                              hipStream_t stream) {
  const float* x = (const float*)d_in[0];
  const int* sidx = (const int*)d_in[1];
  const float* A_all = (const float*)d_in[2];
  const float* C_all = (const float*)d_in[3];
  float* out = (float*)d_out;

  ssm_fused<<<512, 256, 0, stream>>>(x, sidx, A_all, C_all, out);
}